// Round 3
// baseline (145.846 us; speedup 1.0000x reference)
//
#include <hip/hip_runtime.h>
#include <math.h>

#define B_ 8
#define N_ 16384
#define M_ 128
#define C_ 81
#define TPB 512
#define KPT 32              // keys per thread = N_/TPB
#define NWAVE (TPB / 64)    // 8

// ============ Kernel 1: GT hbb prep + out zeroing ============
// hbb8: [B][M][8] = x1,y1,x2,y2,area,pad,pad,pad  (32B stride for aligned s_loads)
__global__ __launch_bounds__(256)
void prep_gt(const float* __restrict__ rt, float* __restrict__ hbb8,
             float* __restrict__ out) {
    int g = blockIdx.x * blockDim.x + threadIdx.x;
    if (blockIdx.x == 0 && threadIdx.x < 3) out[threadIdx.x] = 0.0f;
    if (g >= B_ * M_) return;
    const float* v = rt + (size_t)g * 8;
    float x0 = v[0], y0 = v[1], x1 = v[2], y1 = v[3];
    float x2 = v[4], y2 = v[5], x3 = v[6], y3 = v[7];
    float mnx = fminf(fminf(x0, x1), fminf(x2, x3));
    float mny = fminf(fminf(y0, y1), fminf(y2, y3));
    float mxx = fmaxf(fmaxf(x0, x1), fmaxf(x2, x3));
    float mxy = fmaxf(fmaxf(y0, y1), fmaxf(y2, y3));
    float* o = hbb8 + (size_t)g * 8;
    o[0] = mnx; o[1] = mny; o[2] = mxx; o[3] = mxy;
    o[4] = (mxx - mnx) * (mxy - mny);
    o[5] = 0.f; o[6] = 0.f; o[7] = 0.f;
}

// ============ Kernel 2: IoU + argmax (GT via uniform/scalar loads) ============
__global__ __launch_bounds__(256)
void iou_kernel(const float* __restrict__ bp, const float* __restrict__ hbb8,
                float* __restrict__ miou, int* __restrict__ match) {
    int b = blockIdx.y;
    int n = blockIdx.x * blockDim.x + threadIdx.x;
    const float* p = bp + ((size_t)b * N_ + n) * 5;
    float cx = p[0], cy = p[1], w = p[2], h = p[3], a = p[4];
    float c = cosf(a), s = sinf(a);
    float dx = w * 0.5f, dy = h * 0.5f;
    float ex = fabsf(dx * c) + fabsf(dy * s);
    float ey = fabsf(dx * s) + fabsf(dy * c);
    float ax1 = cx - ex, ay1 = cy - ey, ax2 = cx + ex, ay2 = cy + ey;
    float area_a = (ax2 - ax1) * (ay2 - ay1);

    const float* gbase = hbb8 + (size_t)b * M_ * 8;   // block-uniform
    float bin = -1.0f, bun = 1.0f;                    // best = bin/bun
    int bm = 0;
#pragma unroll 4
    for (int m = 0; m < M_; m++) {
        float bx1 = gbase[m * 8 + 0], by1 = gbase[m * 8 + 1];
        float bx2 = gbase[m * 8 + 2], by2 = gbase[m * 8 + 3];
        float ab  = gbase[m * 8 + 4];
        float lx = fmaxf(ax1, bx1), ly = fmaxf(ay1, by1);
        float rx = fminf(ax2, bx2), ry = fminf(ay2, by2);
        float ww = fmaxf(rx - lx, 0.0f), hh = fmaxf(ry - ly, 0.0f);
        float inter = ww * hh;
        float uni = fmaxf(area_a + ab - inter, 1e-7f);
        bool better = inter * bun > bin * uni;
        bin = better ? inter : bin;
        bun = better ? uni : bun;
        bm = better ? m : bm;
    }
    miou[(size_t)b * N_ + n] = bin / bun;
    match[(size_t)b * N_ + n] = bm;
}

// ============ ballot-based block sum (c <= 63), no shuffles ============
__device__ __forceinline__ unsigned wave_sum6(unsigned c) {
    unsigned s = 0;
#pragma unroll
    for (int bit = 0; bit < 6; bit++)
        s += (unsigned)__popcll(__ballot((c >> bit) & 1u)) << bit;
    return s;
}

__device__ __forceinline__ unsigned bsum(unsigned c, unsigned* slot) {
    unsigned ws = wave_sum6(c);
    if ((threadIdx.x & 63) == 0) slot[threadIdx.x >> 6] = ws;
    __syncthreads();
    unsigned r = 0;
#pragma unroll
    for (int i = 0; i < NWAVE; i++) r += slot[i];
    return r;
}

// ============ Kernel 3: exact top-k selection + loss + atomic out ============
// blockIdx.x: 0 = positives (iou desc, idx asc), 1 = negatives (iou asc, idx asc)
__global__ __launch_bounds__(TPB)
void select_loss(const float* __restrict__ miou, const int* __restrict__ match,
                 const float* __restrict__ logits, const float* __restrict__ bp,
                 const float* __restrict__ rt, const int* __restrict__ labels,
                 const int* __restrict__ ns_ptr, float* __restrict__ out) {
    int type = blockIdx.x;
    int b = blockIdx.y;
    __shared__ float s_cv2[5][M_];
    __shared__ unsigned red[2 * NWAVE] __attribute__((aligned(16)));
    __shared__ float fredc[NWAVE], fredr[NWAVE];
    __shared__ unsigned sel[256];
    __shared__ unsigned selcnt;

    int tid = threadIdx.x;
    int lane = tid & 63, wv = tid >> 6;
    if (tid == 0) selcnt = 0;

    if (tid < M_) {
        const float* v = rt + ((size_t)b * M_ + tid) * 8;
        float x0 = v[0], y0 = v[1], x1 = v[2], y1 = v[3];
        float x2 = v[4], y2 = v[5], x3 = v[6], y3 = v[7];
        s_cv2[0][tid] = (x0 + x1 + x2 + x3) * 0.25f;
        s_cv2[1][tid] = (y0 + y1 + y2 + y3) * 0.25f;
        float e1x = x1 - x0, e1y = y1 - y0;
        float e2x = x3 - x0, e2y = y3 - y0;
        s_cv2[2][tid] = sqrtf(e1x * e1x + e1y * e1y);
        s_cv2[3][tid] = sqrtf(e2x * e2x + e2y * e2y);
        s_cv2[4][tid] = atan2f(e1y, e1x);
    }

    int ns = ns_ptr[0];
    unsigned ktar = (type == 0) ? (unsigned)(ns / 2) : (unsigned)(ns - ns / 2);
    if (ktar > 256u) ktar = 256u;

    // ---- load KPT ious (float4), build order keys ----
    const float4* mi4 = (const float4*)(miou + (size_t)b * N_);
    int base = tid * KPT;
    unsigned key[KPT];
    unsigned vcnt = 0;
#pragma unroll
    for (int q = 0; q < KPT / 4; q++) {
        float4 v4 = mi4[tid * (KPT / 4) + q];
        float io[4] = {v4.x, v4.y, v4.z, v4.w};
#pragma unroll
        for (int j = 0; j < 4; j++) {
            bool pos = (io[j] >= 0.5f);
            unsigned k;
            if (type == 0) {
                if (pos) { k = ~(__float_as_uint(io[j]) | 0x80000000u); vcnt++; }
                else k = 0xFFFFFFFFu;
            } else {
                if (!pos) { k = __float_as_uint(io[j]) | 0x80000000u; vcnt++; }
                else k = 0xFFFFFFFFu;
            }
            key[q * 4 + j] = k;
        }
    }
    __syncthreads();  // selcnt + s_cv2 visible

    int pc = 0;
    unsigned V = bsum(vcnt, red + NWAVE * ((pc++) & 1));
    unsigned keff = (ktar < V) ? ktar : V;

    if (keff == V) {
        // fast path: every valid item selected (order irrelevant — sum)
#pragma unroll
        for (int j = 0; j < KPT; j++) {
            if (key[j] != 0xFFFFFFFFu) {
                unsigned p = atomicAdd(&selcnt, 1u);
                sel[p] = (unsigned)(base + j);
            }
        }
    } else {
        unsigned Ckey;
        bool found = false;
        if (type == 1) {
            // negatives: min possible key is 0x80000000 (iou==0); nothing below.
            unsigned cmin = 0;
#pragma unroll
            for (int j = 0; j < KPT; j++) cmin += (key[j] <= 0x80000000u) ? 1u : 0u;
            unsigned tot = bsum(cmin, red + NWAVE * ((pc++) & 1));
            if (tot >= keff) { Ckey = 0x80000000u; found = true; }
        }
        if (!found) {
            unsigned lo = 0, hi = 0xFFFFFFFFu;
            while (lo < hi) {
                unsigned mid = lo + ((hi - lo) >> 1);
                unsigned c = 0;
#pragma unroll
                for (int j = 0; j < KPT; j++) c += (key[j] <= mid) ? 1u : 0u;
                unsigned tot = bsum(c, red + NWAVE * ((pc++) & 1));
                if (tot >= keff) hi = mid; else lo = mid + 1;
            }
            Ckey = lo;
        }

        unsigned cl = 0, ce = 0;
#pragma unroll
        for (int j = 0; j < KPT; j++) {
            cl += (key[j] < Ckey) ? 1u : 0u;
            ce += (key[j] == Ckey) ? 1u : 0u;
        }
        unsigned m = bsum(cl, red + NWAVE * ((pc++) & 1));
        unsigned e = keff - m;  // ties to take, ascending index

        // rank of this thread's first tie: wave prefix via shfl (runs once)
        unsigned sc = ce;
#pragma unroll
        for (int o = 1; o < 64; o <<= 1) {
            unsigned t = __shfl_up(sc, o);
            if (lane >= o) sc += t;
        }
        unsigned* slot = red + NWAVE * ((pc++) & 1);
        if (lane == 63) slot[wv] = sc;
        __syncthreads();
        unsigned off = 0;
        for (int i = 0; i < wv; i++) off += slot[i];
        unsigned rank = off + sc - ce;

#pragma unroll
        for (int j = 0; j < KPT; j++) {
            unsigned k = key[j];
            bool s = false;
            if (k < Ckey) s = true;
            else if (k == Ckey) { s = (rank < e); rank++; }
            if (s) {
                unsigned p = atomicAdd(&selcnt, 1u);
                sel[p] = (unsigned)(base + j);
            }
        }
    }
    __syncthreads();
    unsigned total_sel = selcnt;  // == keff

    // ---- loss: 4 threads per sample, 21 logits each ----
    float cls_sum = 0.f, reg_sum = 0.f;
    int q = tid & 3;
    for (unsigned sm = (unsigned)(tid >> 2); sm < total_sel; sm += TPB / 4) {
        unsigned i = sel[sm];
        const float* row = logits + ((size_t)b * N_ + i) * C_;
        int c0 = q * 21;
        int c1 = (c0 + 21 < C_) ? c0 + 21 : C_;
        float mx = -INFINITY;
        for (int c = c0; c < c1; c++) mx = fmaxf(mx, row[c]);
        mx = fmaxf(mx, __shfl_xor(mx, 1));
        mx = fmaxf(mx, __shfl_xor(mx, 2));
        float se = 0.f;
        for (int c = c0; c < c1; c++) se += expf(row[c] - mx);
        se += __shfl_xor(se, 1);
        se += __shfl_xor(se, 2);
        if (q == 0) {
            float lse = mx + logf(se);
            if (type == 0) {
                int g_gt = match[(size_t)b * N_ + i];
                int tc = labels[b * M_ + g_gt];
                cls_sum += lse - row[tc];
                const float* pp = bp + ((size_t)b * N_ + i) * 5;
#pragma unroll
                for (int d = 0; d < 5; d++) {
                    float ad = fabsf(pp[d] - s_cv2[d][g_gt]);
                    reg_sum += (ad < 1.f) ? 0.5f * ad * ad : ad - 0.5f;
                }
            } else {
                cls_sum += lse - row[C_ - 1];
            }
        }
    }

    // ---- final reduce (once): interleaved shfl chains + single barrier ----
#pragma unroll
    for (int o = 32; o; o >>= 1) {
        cls_sum += __shfl_down(cls_sum, o);
        reg_sum += __shfl_down(reg_sum, o);
    }
    if (lane == 0) { fredc[wv] = cls_sum; fredr[wv] = reg_sum; }
    __syncthreads();
    if (tid == 0) {
        float cs = 0.f, rs = 0.f;
#pragma unroll
        for (int i = 0; i < NWAVE; i++) { cs += fredc[i]; rs += fredr[i]; }
        const float invB = 1.0f / (float)B_;
        atomicAdd(&out[0], (cs + rs) * invB);
        atomicAdd(&out[1], cs * invB);
        atomicAdd(&out[2], rs * invB);
    }
}

extern "C" void kernel_launch(void* const* d_in, const int* in_sizes, int n_in,
                              void* d_out, int out_size, void* d_ws, size_t ws_size,
                              hipStream_t stream) {
    const float* box_pred = (const float*)d_in[0];     // [B,N,5]
    const float* class_pred = (const float*)d_in[1];   // [B,N,C]
    const float* reg_tgt = (const float*)d_in[2];      // [B,M,4,2]
    const int* cls_tgt = (const int*)d_in[3];          // [B,M]
    const int* n_samples = (const int*)d_in[4];        // [1]

    float* ws = (float*)d_ws;
    float* hbb8 = ws;                                   // B*M*8 floats (32KB)
    float* miou = hbb8 + (size_t)B_ * M_ * 8;           // B*N (16B-aligned)
    int* match = (int*)(miou + (size_t)B_ * N_);        // B*N
    float* out = (float*)d_out;

    prep_gt<<<(B_ * M_ + 255) / 256, 256, 0, stream>>>(reg_tgt, hbb8, out);
    iou_kernel<<<dim3(N_ / 256, B_), 256, 0, stream>>>(box_pred, hbb8, miou, match);
    select_loss<<<dim3(2, B_), TPB, 0, stream>>>(miou, match, class_pred, box_pred,
                                                 reg_tgt, cls_tgt, n_samples, out);
}

// Round 4
// 130.364 us; speedup vs baseline: 1.1188x; 1.1188x over previous
//
#include <hip/hip_runtime.h>
#include <math.h>

#define B_ 8
#define N_ 16384
#define M_ 128
#define C_ 81
#define TPB 512
#define KPT 32              // keys per thread = N_/TPB
#define NWAVE (TPB / 64)    // 8

// ============ Kernel A: GT hbb prep (in-LDS) + IoU + argmax + out-zeroing ======
__global__ __launch_bounds__(256)
void iou_fused(const float* __restrict__ bp,     // [B,N,5]
               const float* __restrict__ rt,     // [B,M,4,2]
               float* __restrict__ miou,         // [B,N]
               int* __restrict__ match,          // [B,N]
               float* __restrict__ out) {        // [3] zeroed here
    __shared__ float sx1[M_], sy1[M_], sx2[M_], sy2[M_], sab[M_];
    int b = blockIdx.y;
    int n = blockIdx.x * blockDim.x + threadIdx.x;

    if (blockIdx.x == 0 && blockIdx.y == 0 && threadIdx.x < 3)
        out[threadIdx.x] = 0.0f;

    if (threadIdx.x < M_) {
        const float* v = rt + ((size_t)b * M_ + threadIdx.x) * 8;
        float x0 = v[0], y0 = v[1], x1 = v[2], y1 = v[3];
        float x2 = v[4], y2 = v[5], x3 = v[6], y3 = v[7];
        float mnx = fminf(fminf(x0, x1), fminf(x2, x3));
        float mny = fminf(fminf(y0, y1), fminf(y2, y3));
        float mxx = fmaxf(fmaxf(x0, x1), fmaxf(x2, x3));
        float mxy = fmaxf(fmaxf(y0, y1), fmaxf(y2, y3));
        sx1[threadIdx.x] = mnx; sy1[threadIdx.x] = mny;
        sx2[threadIdx.x] = mxx; sy2[threadIdx.x] = mxy;
        sab[threadIdx.x] = (mxx - mnx) * (mxy - mny);
    }
    __syncthreads();

    const float* p = bp + ((size_t)b * N_ + n) * 5;
    float cx = p[0], cy = p[1], w = p[2], h = p[3], a = p[4];
    float c = cosf(a), s = sinf(a);
    float dx = w * 0.5f, dy = h * 0.5f;
    float ex = fabsf(dx * c) + fabsf(dy * s);
    float ey = fabsf(dx * s) + fabsf(dy * c);
    float ax1 = cx - ex, ay1 = cy - ey, ax2 = cx + ex, ay2 = cy + ey;
    float area_a = (ax2 - ax1) * (ay2 - ay1);

    // division-free argmax: best tracked as (inter, uni) pair, init -1/1
    float bin = -1.0f, bun = 1.0f;
    int bm = 0;
#pragma unroll 4
    for (int m = 0; m < M_; m++) {
        float lx = fmaxf(ax1, sx1[m]), ly = fmaxf(ay1, sy1[m]);
        float rx = fminf(ax2, sx2[m]), ry = fminf(ay2, sy2[m]);
        float ww = fmaxf(rx - lx, 0.0f), hh = fmaxf(ry - ly, 0.0f);
        float inter = ww * hh;
        float uni = fmaxf(area_a + sab[m] - inter, 1e-7f);
        bool better = inter * bun > bin * uni;   // iou_m > best (uni>0)
        bin = better ? inter : bin;
        bun = better ? uni : bun;
        bm = better ? m : bm;
    }
    miou[(size_t)b * N_ + n] = bin / bun;
    match[(size_t)b * N_ + n] = bm;
}

// ============ ballot-based block sum (c <= 63), no shuffles ============
__device__ __forceinline__ unsigned wave_sum6(unsigned c) {
    unsigned s = 0;
#pragma unroll
    for (int bit = 0; bit < 6; bit++)
        s += (unsigned)__popcll(__ballot((c >> bit) & 1u)) << bit;
    return s;
}

__device__ __forceinline__ unsigned bsum(unsigned c, unsigned* slot) {
    unsigned ws = wave_sum6(c);
    if ((threadIdx.x & 63) == 0) slot[threadIdx.x >> 6] = ws;
    __syncthreads();
    unsigned r = 0;
#pragma unroll
    for (int i = 0; i < NWAVE; i++) r += slot[i];
    return r;
}

// ============ Kernel B: exact top-k selection + loss + atomic out ============
// blockIdx.x: 0 = positives (iou desc, idx asc), 1 = negatives (iou asc, idx asc)
__global__ __launch_bounds__(TPB)
void select_loss(const float* __restrict__ miou, const int* __restrict__ match,
                 const float* __restrict__ logits, const float* __restrict__ bp,
                 const float* __restrict__ rt, const int* __restrict__ labels,
                 const int* __restrict__ ns_ptr, float* __restrict__ out) {
    int type = blockIdx.x;
    int b = blockIdx.y;
    __shared__ float s_cv2[5][M_];
    __shared__ unsigned red[2 * NWAVE] __attribute__((aligned(16)));
    __shared__ float fredc[NWAVE], fredr[NWAVE];
    __shared__ unsigned sel[256];
    __shared__ unsigned selcnt;

    int tid = threadIdx.x;
    int lane = tid & 63, wv = tid >> 6;
    if (tid == 0) selcnt = 0;

    if (tid < M_) {
        const float* v = rt + ((size_t)b * M_ + tid) * 8;
        float x0 = v[0], y0 = v[1], x1 = v[2], y1 = v[3];
        float x2 = v[4], y2 = v[5], x3 = v[6], y3 = v[7];
        s_cv2[0][tid] = (x0 + x1 + x2 + x3) * 0.25f;
        s_cv2[1][tid] = (y0 + y1 + y2 + y3) * 0.25f;
        float e1x = x1 - x0, e1y = y1 - y0;
        float e2x = x3 - x0, e2y = y3 - y0;
        s_cv2[2][tid] = sqrtf(e1x * e1x + e1y * e1y);
        s_cv2[3][tid] = sqrtf(e2x * e2x + e2y * e2y);
        s_cv2[4][tid] = atan2f(e1y, e1x);
    }

    int ns = ns_ptr[0];
    unsigned ktar = (type == 0) ? (unsigned)(ns / 2) : (unsigned)(ns - ns / 2);
    if (ktar > 256u) ktar = 256u;

    // ---- load KPT ious (float4), build order keys ----
    const float4* mi4 = (const float4*)(miou + (size_t)b * N_);
    int base = tid * KPT;
    unsigned key[KPT];
    unsigned vcnt = 0;
#pragma unroll
    for (int q = 0; q < KPT / 4; q++) {
        float4 v4 = mi4[tid * (KPT / 4) + q];
        float io[4] = {v4.x, v4.y, v4.z, v4.w};
#pragma unroll
        for (int j = 0; j < 4; j++) {
            bool pos = (io[j] >= 0.5f);
            unsigned k;
            if (type == 0) {
                if (pos) { k = ~(__float_as_uint(io[j]) | 0x80000000u); vcnt++; }
                else k = 0xFFFFFFFFu;
            } else {
                if (!pos) { k = __float_as_uint(io[j]) | 0x80000000u; vcnt++; }
                else k = 0xFFFFFFFFu;
            }
            key[q * 4 + j] = k;
        }
    }
    __syncthreads();  // selcnt + s_cv2 visible

    int pc = 0;
    unsigned V = bsum(vcnt, red + NWAVE * ((pc++) & 1));
    unsigned keff = (ktar < V) ? ktar : V;

    if (keff == V) {
        // fast path: every valid item selected (order irrelevant — sum)
#pragma unroll
        for (int j = 0; j < KPT; j++) {
            if (key[j] != 0xFFFFFFFFu) {
                unsigned p = atomicAdd(&selcnt, 1u);
                sel[p] = (unsigned)(base + j);
            }
        }
    } else {
        unsigned Ckey;
        bool found = false;
        if (type == 1) {
            // negatives: min possible key is 0x80000000 (iou==0); nothing below.
            unsigned cmin = 0;
#pragma unroll
            for (int j = 0; j < KPT; j++) cmin += (key[j] <= 0x80000000u) ? 1u : 0u;
            unsigned tot = bsum(cmin, red + NWAVE * ((pc++) & 1));
            if (tot >= keff) { Ckey = 0x80000000u; found = true; }
        }
        if (!found) {
            unsigned lo = 0, hi = 0xFFFFFFFFu;
            while (lo < hi) {
                unsigned mid = lo + ((hi - lo) >> 1);
                unsigned c = 0;
#pragma unroll
                for (int j = 0; j < KPT; j++) c += (key[j] <= mid) ? 1u : 0u;
                unsigned tot = bsum(c, red + NWAVE * ((pc++) & 1));
                if (tot >= keff) hi = mid; else lo = mid + 1;
            }
            Ckey = lo;
        }

        unsigned cl = 0, ce = 0;
#pragma unroll
        for (int j = 0; j < KPT; j++) {
            cl += (key[j] < Ckey) ? 1u : 0u;
            ce += (key[j] == Ckey) ? 1u : 0u;
        }
        unsigned m = bsum(cl, red + NWAVE * ((pc++) & 1));
        unsigned e = keff - m;  // ties to take, ascending index

        // rank of this thread's first tie: wave prefix (runs once, not per-round)
        unsigned sc = ce;
#pragma unroll
        for (int o = 1; o < 64; o <<= 1) {
            unsigned t = __shfl_up(sc, o);
            if (lane >= o) sc += t;
        }
        unsigned* slot = red + NWAVE * ((pc++) & 1);
        if (lane == 63) slot[wv] = sc;
        __syncthreads();
        unsigned off = 0;
        for (int i = 0; i < wv; i++) off += slot[i];
        unsigned rank = off + sc - ce;

#pragma unroll
        for (int j = 0; j < KPT; j++) {
            unsigned k = key[j];
            bool s = false;
            if (k < Ckey) s = true;
            else if (k == Ckey) { s = (rank < e); rank++; }
            if (s) {
                unsigned p = atomicAdd(&selcnt, 1u);
                sel[p] = (unsigned)(base + j);
            }
        }
    }
    __syncthreads();
    unsigned total_sel = selcnt;  // == keff

    // ---- loss: 4 threads per sample, 21 logits each ----
    float cls_sum = 0.f, reg_sum = 0.f;
    int q = tid & 3;
    for (unsigned sm = (unsigned)(tid >> 2); sm < total_sel; sm += TPB / 4) {
        unsigned i = sel[sm];
        const float* row = logits + ((size_t)b * N_ + i) * C_;
        int c0 = q * 21;
        int c1 = (c0 + 21 < C_) ? c0 + 21 : C_;
        float mx = -INFINITY;
        for (int c = c0; c < c1; c++) mx = fmaxf(mx, row[c]);
        mx = fmaxf(mx, __shfl_xor(mx, 1));
        mx = fmaxf(mx, __shfl_xor(mx, 2));
        float se = 0.f;
        for (int c = c0; c < c1; c++) se += expf(row[c] - mx);
        se += __shfl_xor(se, 1);
        se += __shfl_xor(se, 2);
        if (q == 0) {
            float lse = mx + logf(se);
            if (type == 0) {
                int g_gt = match[(size_t)b * N_ + i];
                int tc = labels[b * M_ + g_gt];
                cls_sum += lse - row[tc];
                const float* pp = bp + ((size_t)b * N_ + i) * 5;
#pragma unroll
                for (int d = 0; d < 5; d++) {
                    float ad = fabsf(pp[d] - s_cv2[d][g_gt]);
                    reg_sum += (ad < 1.f) ? 0.5f * ad * ad : ad - 0.5f;
                }
            } else {
                cls_sum += lse - row[C_ - 1];
            }
        }
    }

    // ---- final reduce: interleaved shfl chains + single barrier ----
#pragma unroll
    for (int o = 32; o; o >>= 1) {
        cls_sum += __shfl_down(cls_sum, o);
        reg_sum += __shfl_down(reg_sum, o);
    }
    if (lane == 0) { fredc[wv] = cls_sum; fredr[wv] = reg_sum; }
    __syncthreads();
    if (tid == 0) {
        float cs = 0.f, rs = 0.f;
#pragma unroll
        for (int i = 0; i < NWAVE; i++) { cs += fredc[i]; rs += fredr[i]; }
        const float invB = 1.0f / (float)B_;
        atomicAdd(&out[0], (cs + rs) * invB);
        atomicAdd(&out[1], cs * invB);
        atomicAdd(&out[2], rs * invB);
    }
}

extern "C" void kernel_launch(void* const* d_in, const int* in_sizes, int n_in,
                              void* d_out, int out_size, void* d_ws, size_t ws_size,
                              hipStream_t stream) {
    const float* box_pred = (const float*)d_in[0];     // [B,N,5]
    const float* class_pred = (const float*)d_in[1];   // [B,N,C]
    const float* reg_tgt = (const float*)d_in[2];      // [B,M,4,2]
    const int* cls_tgt = (const int*)d_in[3];          // [B,M]
    const int* n_samples = (const int*)d_in[4];        // [1]

    float* ws = (float*)d_ws;
    float* miou = ws;                                  // B*N (16B aligned)
    int* match = (int*)(miou + (size_t)B_ * N_);       // B*N
    float* out = (float*)d_out;

    iou_fused<<<dim3(N_ / 256, B_), 256, 0, stream>>>(box_pred, reg_tgt, miou, match, out);
    select_loss<<<dim3(2, B_), TPB, 0, stream>>>(miou, match, class_pred, box_pred,
                                                 reg_tgt, cls_tgt, n_samples, out);
}